// Round 1
// baseline (1762.506 us; speedup 1.0000x reference)
//
#include <hip/hip_runtime.h>

// MultiLatentHeadAttention on gfx950.
// All heavy GEMMs use split-bf16 (hi/lo) 3-term MFMA emulation of fp32 matmul:
//   A*B ~= Ah*Bh + Ah*Bl + Al*Bh  (error ~2^-16 relative, threshold needs ~2^-12)
// Weights are pre-transposed+split once per call into ws ([N x K] bf16 hi/lo),
// A operands are split on the fly during LDS staging.

#define SEQ      4096
#define BATCH    4
#define NHEADS   16
#define SCALE    0.125f   // 1/sqrt(64)

typedef short bfrag __attribute__((ext_vector_type(8)));  // 8 x bf16
typedef float facc  __attribute__((ext_vector_type(4)));  // 4 x f32 accumulator

__device__ __forceinline__ unsigned short f2bf(float f) {
  unsigned u = __float_as_uint(f);
  u += 0x7FFFu + ((u >> 16) & 1u);           // round-to-nearest-even
  return (unsigned short)(u >> 16);
}
__device__ __forceinline__ float bf2f(unsigned short h) {
  return __uint_as_float(((unsigned)h) << 16);
}
// pack two floats into one dword of bf16-hi, return it; lo dword via ref
__device__ __forceinline__ unsigned pack_hl(float a, float b, unsigned &lo) {
  unsigned short ha = f2bf(a), hb = f2bf(b);
  unsigned short la = f2bf(a - bf2f(ha)), lb = f2bf(b - bf2f(hb));
  lo = (unsigned)la | ((unsigned)lb << 16);
  return (unsigned)ha | ((unsigned)hb << 16);
}

// ---------------------------------------------------------------------------
// Weight prep: W [K x N] fp32  ->  Th/Tl [N x K] bf16 hi/lo  (transpose+split)
// grid: (K/64, N/64), block 256
// ---------------------------------------------------------------------------
__global__ __launch_bounds__(256) void prep_weight_kernel(
    const float* __restrict__ W, int K, int N,
    unsigned short* __restrict__ Th, unsigned short* __restrict__ Tl)
{
  __shared__ float tile[64][68];
  const int k0 = blockIdx.x * 64, n0 = blockIdx.y * 64;
  const int tid = threadIdx.x;
  const int r = tid >> 2, q = tid & 3;
#pragma unroll
  for (int j = 0; j < 4; j++)
    *(float4*)&tile[r][q*16 + j*4] =
        *(const float4*)&W[(size_t)(k0 + r) * N + n0 + q*16 + j*4];
  __syncthreads();
  const size_t obase = (size_t)(n0 + r) * K + k0 + q*16;
#pragma unroll
  for (int g = 0; g < 2; g++) {
    float f0 = tile[q*16 + g*8 + 0][r];
    float f1 = tile[q*16 + g*8 + 1][r];
    float f2 = tile[q*16 + g*8 + 2][r];
    float f3 = tile[q*16 + g*8 + 3][r];
    float f4 = tile[q*16 + g*8 + 4][r];
    float f5 = tile[q*16 + g*8 + 5][r];
    float f6 = tile[q*16 + g*8 + 6][r];
    float f7 = tile[q*16 + g*8 + 7][r];
    uint4 H, Lo;
    H.x = pack_hl(f0, f1, Lo.x);
    H.y = pack_hl(f2, f3, Lo.y);
    H.z = pack_hl(f4, f5, Lo.z);
    H.w = pack_hl(f6, f7, Lo.w);
    *(uint4*)&Th[obase + g*8] = H;
    *(uint4*)&Tl[obase + g*8] = Lo;
  }
}

// ---------------------------------------------------------------------------
// Split-bf16 GEMM: C[M x N] fp32 = A[M x K] fp32 @ W, with W given as
// Bh/Bl = W^T hi/lo bf16 [N x K]. Block 256 thr = 4 waves (2x2), tile 128x128,
// BK=32, wave computes 64x64 via 4x4 grid of 16x16x32 MFMAs, 3 per product.
// grid: (ceil(M/128), N/128)
// ---------------------------------------------------------------------------
#define SAP 40   // padded k-stride (elements): 32 + 8, keeps 16B alignment

__global__ __launch_bounds__(256) void gemm_split_kernel(
    const float* __restrict__ A,
    const unsigned short* __restrict__ Bh,
    const unsigned short* __restrict__ Bl,
    float* __restrict__ C,
    int M, int N, int K)
{
  __shared__ unsigned short sAh[128*SAP], sAl[128*SAP], sBh[128*SAP], sBl[128*SAP];
  const int tid = threadIdx.x;
  const int m0 = blockIdx.x * 128, n0 = blockIdx.y * 128;
  const int wave = tid >> 6, lane = tid & 63;
  const int lrow = lane & 15, lq = lane >> 4;
  const int wm = (wave & 1) * 64, wn = (wave >> 1) * 64;
  const int sr = tid >> 1, sc = (tid & 1) * 16;
  const bool arow_ok = (m0 + sr) < M;
  const float* Ap = A + (size_t)(m0 + sr) * K + sc;
  const unsigned short* Bhp = Bh + (size_t)(n0 + sr) * K + sc;
  const unsigned short* Blp = Bl + (size_t)(n0 + sr) * K + sc;

  facc acc[4][4] = {};

  for (int k0 = 0; k0 < K; k0 += 32) {
    // ---- stage A: fp32 -> bf16 hi/lo in LDS
#pragma unroll
    for (int g = 0; g < 2; g++) {
      float4 u = make_float4(0.f, 0.f, 0.f, 0.f), v = u;
      if (arow_ok) {
        u = *(const float4*)(Ap + k0 + g*8);
        v = *(const float4*)(Ap + k0 + g*8 + 4);
      }
      uint4 H, Lo;
      H.x = pack_hl(u.x, u.y, Lo.x);
      H.y = pack_hl(u.z, u.w, Lo.y);
      H.z = pack_hl(v.x, v.y, Lo.z);
      H.w = pack_hl(v.z, v.w, Lo.w);
      *(uint4*)&sAh[sr*SAP + sc + g*8] = H;
      *(uint4*)&sAl[sr*SAP + sc + g*8] = Lo;
    }
    // ---- stage B: copy pre-split bf16 hi/lo
    {
      uint4 h0 = *(const uint4*)(Bhp + k0);
      uint4 h1 = *(const uint4*)(Bhp + k0 + 8);
      uint4 l0 = *(const uint4*)(Blp + k0);
      uint4 l1 = *(const uint4*)(Blp + k0 + 8);
      *(uint4*)&sBh[sr*SAP + sc]     = h0;
      *(uint4*)&sBh[sr*SAP + sc + 8] = h1;
      *(uint4*)&sBl[sr*SAP + sc]     = l0;
      *(uint4*)&sBl[sr*SAP + sc + 8] = l1;
    }
    __syncthreads();
    // ---- fragments
    bfrag ah[4], al[4], bhv[4], blv[4];
#pragma unroll
    for (int i = 0; i < 4; i++) {
      int ao = (wm + i*16 + lrow) * SAP + lq*8;
      ah[i] = *(const bfrag*)&sAh[ao];
      al[i] = *(const bfrag*)&sAl[ao];
      int bo = (wn + i*16 + lrow) * SAP + lq*8;
      bhv[i] = *(const bfrag*)&sBh[bo];
      blv[i] = *(const bfrag*)&sBl[bo];
    }
    __syncthreads();
    // ---- 48 MFMAs (16 products x 3 split terms)
#pragma unroll
    for (int mi = 0; mi < 4; mi++)
#pragma unroll
      for (int ni = 0; ni < 4; ni++) {
        acc[mi][ni] = __builtin_amdgcn_mfma_f32_16x16x32_bf16(ah[mi], bhv[ni], acc[mi][ni], 0, 0, 0);
        acc[mi][ni] = __builtin_amdgcn_mfma_f32_16x16x32_bf16(ah[mi], blv[ni], acc[mi][ni], 0, 0, 0);
        acc[mi][ni] = __builtin_amdgcn_mfma_f32_16x16x32_bf16(al[mi], bhv[ni], acc[mi][ni], 0, 0, 0);
      }
  }
  // ---- epilogue: C/D layout col=lane&15, row=(lane>>4)*4+reg
#pragma unroll
  for (int mi = 0; mi < 4; mi++) {
#pragma unroll
    for (int r = 0; r < 4; r++) {
      int row = m0 + wm + mi*16 + lq*4 + r;
      if (row < M) {
        float* Crow = C + (size_t)row * N + n0 + wn + lrow;
#pragma unroll
        for (int ni = 0; ni < 4; ni++)
          Crow[ni*16] = acc[mi][ni][r];
      }
    }
  }
}

// ---------------------------------------------------------------------------
// Stage-1 cross attention (latents attend to 4096 tokens), flash partials.
// grid: (8 chunks, H, B), block 256. Thread t owns latent i=t>>2, 16-col slice.
// KV: [B*T x 2048], K cols 0..1023, V cols 1024..2047.
// ---------------------------------------------------------------------------
__global__ __launch_bounds__(256) void attn1_kernel(
    const float* __restrict__ Qlat,   // [64 x 1024]
    const float* __restrict__ KV,
    float* __restrict__ mPart, float* __restrict__ lPart, float* __restrict__ oPart)
{
  __shared__ float Qs[64][68], Ks[64][68], Vs[64][68];
  float (*Ps)[68] = Ks;  // scores-P reuses K tile (separated by syncs)
  const int tid = threadIdx.x;
  const int chunk = blockIdx.x, h = blockIdx.y, b = blockIdx.z;
  const int i = tid >> 2, q = tid & 3, db = q * 16;
#pragma unroll
  for (int j = 0; j < 4; j++)
    *(float4*)&Qs[i][db + j*4] = *(const float4*)&Qlat[(size_t)i*1024 + h*64 + db + j*4];
  float m_i = -INFINITY, l_i = 0.f;
  float o[16];
#pragma unroll
  for (int dd = 0; dd < 16; dd++) o[dd] = 0.f;
  __syncthreads();

  for (int kt = 0; kt < 8; kt++) {
    const int jg = chunk*512 + kt*64;
    const size_t rb = ((size_t)b*SEQ + jg + i) * 2048;
#pragma unroll
    for (int j = 0; j < 4; j++) {
      *(float4*)&Ks[i][db + j*4] = *(const float4*)&KV[rb + h*64 + db + j*4];
      *(float4*)&Vs[i][db + j*4] = *(const float4*)&KV[rb + 1024 + h*64 + db + j*4];
    }
    __syncthreads();
    float s[16];
#pragma unroll
    for (int jj = 0; jj < 16; jj++) {
      int j = db + jj;
      float d0 = 0.f;
#pragma unroll
      for (int d = 0; d < 64; d += 4) {
        float4 qv = *(const float4*)&Qs[i][d];
        float4 kv = *(const float4*)&Ks[j][d];
        d0 += qv.x*kv.x + qv.y*kv.y + qv.z*kv.z + qv.w*kv.w;
      }
      s[jj] = d0 * SCALE;
    }
    float mt = s[0];
#pragma unroll
    for (int jj = 1; jj < 16; jj++) mt = fmaxf(mt, s[jj]);
    mt = fmaxf(mt, __shfl_xor(mt, 1));
    mt = fmaxf(mt, __shfl_xor(mt, 2));
    const float m_new = fmaxf(m_i, mt);
    const float fac = __expf(m_i - m_new);
    l_i *= fac;
#pragma unroll
    for (int dd = 0; dd < 16; dd++) o[dd] *= fac;
    __syncthreads();              // everyone done reading Ks before P overwrites it
    float ps = 0.f;
#pragma unroll
    for (int jj = 0; jj < 16; jj++) {
      float p = __expf(s[jj] - m_new);
      Ps[i][db + jj] = p;
      ps += p;
    }
    ps += __shfl_xor(ps, 1);
    ps += __shfl_xor(ps, 2);
    l_i += ps;
    m_i = m_new;
    __syncthreads();
    for (int j = 0; j < 64; j++) {
      float w = Ps[i][j];
#pragma unroll
      for (int dd = 0; dd < 16; dd += 4) {
        float4 vv = *(const float4*)&Vs[j][db + dd];
        o[dd+0] += w*vv.x; o[dd+1] += w*vv.y; o[dd+2] += w*vv.z; o[dd+3] += w*vv.w;
      }
    }
    __syncthreads();
  }
  const int bh = b*NHEADS + h;
  const size_t ob = ((size_t)(bh*8 + chunk)*64 + i)*64 + db;
#pragma unroll
  for (int dd = 0; dd < 16; dd++) oPart[ob + dd] = o[dd];
  if (q == 0) {
    mPart[(bh*8 + chunk)*64 + i] = m_i;
    lPart[(bh*8 + chunk)*64 + i] = l_i;
  }
}

// combine 8 flash partials -> z [B*64 x 1024] (merged heads). grid (H, B).
__global__ __launch_bounds__(256) void attn1_combine_kernel(
    const float* __restrict__ mPart, const float* __restrict__ lPart,
    const float* __restrict__ oPart, float* __restrict__ Z)
{
  const int h = blockIdx.x, b = blockIdx.y;
  const int tid = threadIdx.x;
  const int i = tid >> 2, q = tid & 3, db = q * 16;
  const int bh = b*NHEADS + h;
  float mv[8];
  float M = -INFINITY;
#pragma unroll
  for (int c = 0; c < 8; c++) { mv[c] = mPart[(bh*8 + c)*64 + i]; M = fmaxf(M, mv[c]); }
  float Lt = 0.f, w[8];
#pragma unroll
  for (int c = 0; c < 8; c++) { w[c] = __expf(mv[c] - M); Lt += lPart[(bh*8 + c)*64 + i] * w[c]; }
  float o[16];
#pragma unroll
  for (int dd = 0; dd < 16; dd++) o[dd] = 0.f;
#pragma unroll
  for (int c = 0; c < 8; c++) {
    const float* ob = oPart + ((size_t)(bh*8 + c)*64 + i)*64 + db;
#pragma unroll
    for (int dd = 0; dd < 16; dd += 4) {
      float4 v = *(const float4*)(ob + dd);
      o[dd+0] += w[c]*v.x; o[dd+1] += w[c]*v.y; o[dd+2] += w[c]*v.z; o[dd+3] += w[c]*v.w;
    }
  }
  const float inv = 1.f / Lt;
#pragma unroll
  for (int dd = 0; dd < 4; dd++) {
    float4 ov = make_float4(o[dd*4]*inv, o[dd*4+1]*inv, o[dd*4+2]*inv, o[dd*4+3]*inv);
    *(float4*)&Z[((size_t)b*64 + i)*1024 + h*64 + db + dd*4] = ov;
  }
}

// ---------------------------------------------------------------------------
// Small attention (64 keys = latents), used for stage 2 and stage 3.
// grid: (q_tiles, H, B), block 256. One 64-row Q tile per block, full softmax.
// ---------------------------------------------------------------------------
__global__ __launch_bounds__(256) void attn_small_kernel(
    const float* __restrict__ Qp, int ldq, int qrows_per_b,
    const float* __restrict__ Kp, int ldk,
    const float* __restrict__ Vp, int ldv,
    float* __restrict__ Op, int ldo)
{
  __shared__ float Qs[64][68], Ks[64][68], Vs[64][68];
  float (*Ps)[68] = Ks;
  const int tid = threadIdx.x;
  const int tt = blockIdx.x, h = blockIdx.y, b = blockIdx.z;
  const int i = tid >> 2, q = tid & 3, db = q * 16;
  const size_t qrow = (size_t)b*qrows_per_b + (size_t)tt*64 + i;
  const size_t krow = (size_t)b*64 + i;
#pragma unroll
  for (int j = 0; j < 4; j++) {
    *(float4*)&Qs[i][db + j*4] = *(const float4*)&Qp[qrow*ldq + h*64 + db + j*4];
    *(float4*)&Ks[i][db + j*4] = *(const float4*)&Kp[krow*ldk + h*64 + db + j*4];
    *(float4*)&Vs[i][db + j*4] = *(const float4*)&Vp[krow*ldv + h*64 + db + j*4];
  }
  __syncthreads();
  float s[16];
#pragma unroll
  for (int jj = 0; jj < 16; jj++) {
    int j = db + jj;
    float d0 = 0.f;
#pragma unroll
    for (int d = 0; d < 64; d += 4) {
      float4 qv = *(const float4*)&Qs[i][d];
      float4 kv = *(const float4*)&Ks[j][d];
      d0 += qv.x*kv.x + qv.y*kv.y + qv.z*kv.z + qv.w*kv.w;
    }
    s[jj] = d0 * SCALE;
  }
  float m = s[0];
#pragma unroll
  for (int jj = 1; jj < 16; jj++) m = fmaxf(m, s[jj]);
  m = fmaxf(m, __shfl_xor(m, 1));
  m = fmaxf(m, __shfl_xor(m, 2));
  __syncthreads();               // all score reads of Ks done
  float l = 0.f;
#pragma unroll
  for (int jj = 0; jj < 16; jj++) {
    float p = __expf(s[jj] - m);
    Ps[i][db + jj] = p;
    l += p;
  }
  l += __shfl_xor(l, 1);
  l += __shfl_xor(l, 2);
  __syncthreads();
  float o[16];
#pragma unroll
  for (int dd = 0; dd < 16; dd++) o[dd] = 0.f;
  for (int j = 0; j < 64; j++) {
    float w = Ps[i][j];
#pragma unroll
    for (int dd = 0; dd < 16; dd += 4) {
      float4 vv = *(const float4*)&Vs[j][db + dd];
      o[dd+0] += w*vv.x; o[dd+1] += w*vv.y; o[dd+2] += w*vv.z; o[dd+3] += w*vv.w;
    }
  }
  const float inv = 1.f / l;
#pragma unroll
  for (int dd = 0; dd < 4; dd++) {
    float4 ov = make_float4(o[dd*4]*inv, o[dd*4+1]*inv, o[dd*4+2]*inv, o[dd*4+3]*inv);
    *(float4*)&Op[qrow*ldo + h*64 + db + dd*4] = ov;
  }
}

// ---------------------------------------------------------------------------
extern "C" void kernel_launch(void* const* d_in, const int* in_sizes, int n_in,
                              void* d_out, int out_size, void* d_ws, size_t ws_size,
                              hipStream_t stream)
{
  const float* x      = (const float*)d_in[0];
  const float* L      = (const float*)d_in[1];
  const float* Wq_lat = (const float*)d_in[2];
  const float* Wk_in  = (const float*)d_in[3];
  const float* Wv_in  = (const float*)d_in[4];
  const float* Wq_in  = (const float*)d_in[5];
  const float* Wk_lat = (const float*)d_in[6];
  const float* Wv_lat = (const float*)d_in[7];
  const float* Wout   = (const float*)d_in[8];
  float* out = (float*)d_out;
  (void)in_sizes; (void)n_in; (void)out_size; (void)ws_size;

  char* ws = (char*)d_ws;
  size_t off = 0;
  auto alloc = [&](size_t bytes) -> char* {
    char* p = ws + off; off += (bytes + 255) & ~(size_t)255; return p;
  };
  // weights (bf16 hi/lo, transposed). [Wk_in|Wv_in] and [Wq|Wk|Wv]_lat contiguous.
  unsigned short* wtKV_h  = (unsigned short*)alloc(2048ull*2048*2);
  unsigned short* wtKV_l  = (unsigned short*)alloc(2048ull*2048*2);
  unsigned short* wtQin_h = (unsigned short*)alloc(1024ull*2048*2);
  unsigned short* wtQin_l = (unsigned short*)alloc(1024ull*2048*2);
  unsigned short* wtLat_h = (unsigned short*)alloc(3072ull*1024*2);
  unsigned short* wtLat_l = (unsigned short*)alloc(3072ull*1024*2);
  unsigned short* wtOut_h = (unsigned short*)alloc(2048ull*1024*2);
  unsigned short* wtOut_l = (unsigned short*)alloc(2048ull*1024*2);
  float* qlat  = (float*)alloc(64ull*1024*4);
  float* z     = (float*)alloc(256ull*1024*4);
  float* zqkv  = (float*)alloc(256ull*3072*4);
  float* z2    = (float*)alloc(256ull*1024*4);
  float* z2kv  = (float*)alloc(256ull*2048*4);
  float* mPart = (float*)alloc(4ull*16*8*64*4);
  float* lPart = (float*)alloc(4ull*16*8*64*4);
  float* oPart = (float*)alloc(4ull*16*8*64*64*4);
  float* big   = (float*)alloc(16384ull*2048*4);   // phase 1: [K|V]; phase 2: Qx + x_latent
  float* qx    = big;                              // 16384 x 1024 (K region, V dead by then)
  float* xlat  = big + 16384ull*1024;              // 16384 x 1024

  dim3 blk(256);

  // 1) weight prep
  prep_weight_kernel<<<dim3(32, 16), blk, 0, stream>>>(Wk_in, 2048, 1024, wtKV_h, wtKV_l);
  prep_weight_kernel<<<dim3(32, 16), blk, 0, stream>>>(Wv_in, 2048, 1024, wtKV_h + 1024ull*2048, wtKV_l + 1024ull*2048);
  prep_weight_kernel<<<dim3(32, 16), blk, 0, stream>>>(Wq_in, 2048, 1024, wtQin_h, wtQin_l);
  prep_weight_kernel<<<dim3(16, 16), blk, 0, stream>>>(Wq_lat, 1024, 1024, wtLat_h, wtLat_l);
  prep_weight_kernel<<<dim3(16, 16), blk, 0, stream>>>(Wk_lat, 1024, 1024, wtLat_h + 1024ull*1024, wtLat_l + 1024ull*1024);
  prep_weight_kernel<<<dim3(16, 16), blk, 0, stream>>>(Wv_lat, 1024, 1024, wtLat_h + 2048ull*1024, wtLat_l + 2048ull*1024);
  prep_weight_kernel<<<dim3(16, 32), blk, 0, stream>>>(Wout, 1024, 2048, wtOut_h, wtOut_l);

  // 2) Q_lat = L @ W_q_lat (batch-independent), [64 x 1024]
  gemm_split_kernel<<<dim3(1, 8), blk, 0, stream>>>(L, wtLat_h, wtLat_l, qlat, 64, 1024, 1024);
  // 3) [K|V] = x @ [Wk_in|Wv_in], [16384 x 2048]
  gemm_split_kernel<<<dim3(128, 16), blk, 0, stream>>>(x, wtKV_h, wtKV_l, big, 16384, 2048, 2048);
  // 4) stage-1 attention (flash over 4096 keys) -> z [256 x 1024]
  attn1_kernel<<<dim3(8, 16, 4), blk, 0, stream>>>(qlat, big, mPart, lPart, oPart);
  attn1_combine_kernel<<<dim3(16, 4), blk, 0, stream>>>(mPart, lPart, oPart, z);
  // 5) [Ql|Kl|Vl] = z @ [Wq_lat|Wk_lat|Wv_lat], [256 x 3072]
  gemm_split_kernel<<<dim3(2, 24), blk, 0, stream>>>(z, wtLat_h, wtLat_l, zqkv, 256, 3072, 1024);
  // 6) stage-2 latent self-attention -> z2 [256 x 1024]
  attn_small_kernel<<<dim3(1, 16, 4), blk, 0, stream>>>(zqkv, 3072, 64, zqkv + 1024, 3072, zqkv + 2048, 3072, z2, 1024);
  // 7) [Kz|Vz] = z2 @ [Wk_lat|Wv_lat], [256 x 2048]
  gemm_split_kernel<<<dim3(2, 16), blk, 0, stream>>>(z2, wtLat_h + 1024ull*1024, wtLat_l + 1024ull*1024, z2kv, 256, 2048, 1024);
  // 8) Qx = x @ Wq_in, [16384 x 1024] (reuses K region)
  gemm_split_kernel<<<dim3(128, 8), blk, 0, stream>>>(x, wtQin_h, wtQin_l, qx, 16384, 1024, 2048);
  // 9) stage-3 attention (tokens attend to 64 latents) -> x_latent
  attn_small_kernel<<<dim3(64, 16, 4), blk, 0, stream>>>(qx, 1024, 4096, z2kv, 2048, z2kv + 1024, 2048, xlat, 1024);
  // 10) out = x_latent @ W_out, [16384 x 2048]
  gemm_split_kernel<<<dim3(128, 16), blk, 0, stream>>>(xlat, wtOut_h, wtOut_l, out, 16384, 2048, 1024);
}

// Round 2
// 1348.419 us; speedup vs baseline: 1.3071x; 1.3071x over previous
//
#include <hip/hip_runtime.h>

// MultiLatentHeadAttention on gfx950 — round 2.
// All heavy GEMMs: split-bf16 (hi/lo) 3-term MFMA emulation of fp32 matmul.
// A operands are pre-split into global bf16 hi/lo (x/L via a split pass;
// z/z2/x_latent written split directly by the attention kernels), so GEMM
// staging is pure global_load_lds (width 16) for all 4 streams.
// GEMM: block 256 thr = 4 waves, block tile 256(M)x128(N), wave tile 128x64,
// BK=32, 96 MFMA per wave-iter vs 24KB LDS frag reads (0.25 KB/MFMA).

#define SEQ      4096
#define NHEADS   16
#define SCALE    0.125f   // 1/sqrt(64)

typedef short bfrag __attribute__((ext_vector_type(8)));  // 8 x bf16
typedef float facc  __attribute__((ext_vector_type(4)));  // 4 x f32 accumulator

__device__ __forceinline__ unsigned short f2bf(float f) {
  unsigned u = __float_as_uint(f);
  u += 0x7FFFu + ((u >> 16) & 1u);           // round-to-nearest-even
  return (unsigned short)(u >> 16);
}
__device__ __forceinline__ float bf2f(unsigned short h) {
  return __uint_as_float(((unsigned)h) << 16);
}
__device__ __forceinline__ unsigned pack_hl(float a, float b, unsigned &lo) {
  unsigned short ha = f2bf(a), hb = f2bf(b);
  unsigned short la = f2bf(a - bf2f(ha)), lb = f2bf(b - bf2f(hb));
  lo = (unsigned)la | ((unsigned)lb << 16);
  return (unsigned)ha | ((unsigned)hb << 16);
}

__device__ __forceinline__ void gl_lds16(const void* g, void* l) {
  __builtin_amdgcn_global_load_lds(
      (const __attribute__((address_space(1))) void*)g,
      (__attribute__((address_space(3))) void*)l, 16, 0, 0);
}

// write 16 fp32 (scaled by inv) as bf16 hi/lo, 2x uint4 each
__device__ __forceinline__ void write_split16(unsigned short* Hp, unsigned short* Lp,
                                              const float* o, float inv) {
  uint4 H0, H1, L0, L1;
  unsigned* Hw = &H0.x; unsigned* Lw = &L0.x;
#pragma unroll
  for (int k = 0; k < 8; k++) {
    unsigned lo;
    unsigned hi = pack_hl(o[2*k] * inv, o[2*k+1] * inv, lo);
    if (k < 4) { (&H0.x)[k] = hi; (&L0.x)[k] = lo; }
    else       { (&H1.x)[k-4] = hi; (&L1.x)[k-4] = lo; }
  }
  (void)Hw; (void)Lw;
  *(uint4*)Hp       = H0;
  *(uint4*)(Hp + 8) = H1;
  *(uint4*)Lp       = L0;
  *(uint4*)(Lp + 8) = L1;
}

// ---------------------------------------------------------------------------
// Weight prep: W [K x N] fp32 -> Th/Tl [N x K] bf16 hi/lo (transpose+split)
// grid: (K/64, N/64), block 256
// ---------------------------------------------------------------------------
__global__ __launch_bounds__(256) void prep_weight_kernel(
    const float* __restrict__ W, int K, int N,
    unsigned short* __restrict__ Th, unsigned short* __restrict__ Tl)
{
  __shared__ float tile[64][68];
  const int k0 = blockIdx.x * 64, n0 = blockIdx.y * 64;
  const int tid = threadIdx.x;
  const int r = tid >> 2, q = tid & 3;
#pragma unroll
  for (int j = 0; j < 4; j++)
    *(float4*)&tile[r][q*16 + j*4] =
        *(const float4*)&W[(size_t)(k0 + r) * N + n0 + q*16 + j*4];
  __syncthreads();
  const size_t obase = (size_t)(n0 + r) * K + k0 + q*16;
#pragma unroll
  for (int g = 0; g < 2; g++) {
    float f[8];
#pragma unroll
    for (int e = 0; e < 8; e++) f[e] = tile[q*16 + g*8 + e][r];
    uint4 H, Lo;
    H.x = pack_hl(f[0], f[1], Lo.x);
    H.y = pack_hl(f[2], f[3], Lo.y);
    H.z = pack_hl(f[4], f[5], Lo.z);
    H.w = pack_hl(f[6], f[7], Lo.w);
    *(uint4*)&Th[obase + g*8] = H;
    *(uint4*)&Tl[obase + g*8] = Lo;
  }
}

// ---------------------------------------------------------------------------
// Split fp32 array -> bf16 hi/lo (same layout). One thread per 8 elements.
// ---------------------------------------------------------------------------
__global__ __launch_bounds__(256) void split_f32_kernel(
    const float* __restrict__ X, unsigned short* __restrict__ H,
    unsigned short* __restrict__ Lo, int n8)
{
  int idx = blockIdx.x * 256 + threadIdx.x;
  if (idx >= n8) return;
  const float4 a = *(const float4*)&X[(size_t)idx*8];
  const float4 b = *(const float4*)&X[(size_t)idx*8 + 4];
  uint4 Hh, Ll;
  Hh.x = pack_hl(a.x, a.y, Ll.x);
  Hh.y = pack_hl(a.z, a.w, Ll.y);
  Hh.z = pack_hl(b.x, b.y, Ll.z);
  Hh.w = pack_hl(b.z, b.w, Ll.w);
  *(uint4*)&H[(size_t)idx*8]  = Hh;
  *(uint4*)&Lo[(size_t)idx*8] = Ll;
}

// ---------------------------------------------------------------------------
// Split-bf16 GEMM, pure-DMA staging.
// C[MxN] fp32 = A (hi/lo bf16 [MxK]) @ B^T (hi/lo bf16 [NxK]).
// Block 256 thr / 4 waves; block tile 256x128; wave tile 128x64 (2m x 2n);
// BK=32. grid: (ceil(M/256), N/128). M<256 handled by row clamping.
// ---------------------------------------------------------------------------
__global__ __launch_bounds__(256, 2) void gemm_dma_kernel(
    const unsigned short* __restrict__ Ah, const unsigned short* __restrict__ Al,
    const unsigned short* __restrict__ Bh, const unsigned short* __restrict__ Bl,
    float* __restrict__ C, int M, int N, int K)
{
  __shared__ unsigned short sAh[256*32], sAl[256*32], sBh[128*32], sBl[128*32];
  const int tid = threadIdx.x;
  const int m0 = blockIdx.x * 256, n0 = blockIdx.y * 128;
  const int wave = tid >> 6, lane = tid & 63;
  const int lrow = lane & 15, lq = lane >> 4;
  const int wm = (wave & 1) * 128, wn = (wave >> 1) * 64;

  // staging geometry: each wave-instr moves 16 rows x 64B (lane -> row i>>2, chunk i&3)
  const int srow = lane >> 2, schunk = lane & 3;
  size_t aoff[4], boff[2];
#pragma unroll
  for (int j = 0; j < 4; j++) {
    int rg = m0 + 64*wave + 16*j + srow;
    if (rg > M-1) rg = M-1;
    aoff[j] = ((size_t)rg * K + schunk*8) * 2;
  }
#pragma unroll
  for (int j = 0; j < 2; j++) {
    int rg = n0 + 32*wave + 16*j + srow;
    boff[j] = ((size_t)rg * K + schunk*8) * 2;
  }
  const char* Ahc = (const char*)Ah;  const char* Alc = (const char*)Al;
  const char* Bhc = (const char*)Bh;  const char* Blc = (const char*)Bl;

  facc acc[8][4] = {};

  for (int k0 = 0; k0 < K; k0 += 32) {
    const size_t kb = (size_t)k0 * 2;
#pragma unroll
    for (int j = 0; j < 4; j++) {
      gl_lds16(Ahc + aoff[j] + kb, (char*)sAh + (64*wave + 16*j)*64);
      gl_lds16(Alc + aoff[j] + kb, (char*)sAl + (64*wave + 16*j)*64);
    }
#pragma unroll
    for (int j = 0; j < 2; j++) {
      gl_lds16(Bhc + boff[j] + kb, (char*)sBh + (32*wave + 16*j)*64);
      gl_lds16(Blc + boff[j] + kb, (char*)sBl + (32*wave + 16*j)*64);
    }
    __syncthreads();   // drains vmcnt(0): DMA complete + all waves at barrier

    bfrag bh[4], bl[4];
#pragma unroll
    for (int ni = 0; ni < 4; ni++) {
      const int bo = (wn + ni*16 + lrow)*32 + lq*8;
      bh[ni] = *(const bfrag*)&sBh[bo];
      bl[ni] = *(const bfrag*)&sBl[bo];
    }
#pragma unroll
    for (int mi = 0; mi < 8; mi++) {
      const int ao = (wm + mi*16 + lrow)*32 + lq*8;
      const bfrag ah = *(const bfrag*)&sAh[ao];
      const bfrag al = *(const bfrag*)&sAl[ao];
#pragma unroll
      for (int ni = 0; ni < 4; ni++) {
        acc[mi][ni] = __builtin_amdgcn_mfma_f32_16x16x32_bf16(ah, bh[ni], acc[mi][ni], 0, 0, 0);
        acc[mi][ni] = __builtin_amdgcn_mfma_f32_16x16x32_bf16(ah, bl[ni], acc[mi][ni], 0, 0, 0);
        acc[mi][ni] = __builtin_amdgcn_mfma_f32_16x16x32_bf16(al, bh[ni], acc[mi][ni], 0, 0, 0);
      }
    }
    __syncthreads();   // all waves done reading LDS before next DMA lands
  }

  // epilogue: C/D layout col=lane&15, row=(lane>>4)*4+reg
#pragma unroll
  for (int mi = 0; mi < 8; mi++) {
#pragma unroll
    for (int r = 0; r < 4; r++) {
      const int row = m0 + wm + mi*16 + lq*4 + r;
      if (row < M) {
        float* Crow = C + (size_t)row * N + n0 + wn + lrow;
#pragma unroll
        for (int ni = 0; ni < 4; ni++)
          Crow[ni*16] = acc[mi][ni][r];
      }
    }
  }
}

// ---------------------------------------------------------------------------
// Stage-1 cross attention (64 latents attend to 4096 tokens), flash partials.
// grid: (8 chunks, H, B), block 256. Thread t: latent i=t>>2, col-quarter q.
// Q held in registers (d-rotated by 20q to kill LDS bank conflicts on Ks).
// ---------------------------------------------------------------------------
__global__ __launch_bounds__(256) void attn1_kernel(
    const float* __restrict__ Qlat,   // [64 x 1024]
    const float* __restrict__ KV,     // [B*T x 2048], K cols 0..1023, V 1024..2047
    float* __restrict__ mPart, float* __restrict__ lPart, float* __restrict__ oPart)
{
  __shared__ float Ks[64][68], Vs[64][68], Ps[64][68];
  const int tid = threadIdx.x;
  const int chunk = blockIdx.x, h = blockIdx.y, b = blockIdx.z;
  const int i = tid >> 2, q = tid & 3, db = q * 16, rot = q * 20;

  float4 qreg[16];
#pragma unroll
  for (int dd = 0; dd < 16; dd++) {
    const int c = (4*dd + rot) & 63;
    qreg[dd] = *(const float4*)&Qlat[(size_t)i*1024 + h*64 + c];
  }
  float m_i = -__builtin_inff(), l_i = 0.f;
  float o[16];
#pragma unroll
  for (int dd = 0; dd < 16; dd++) o[dd] = 0.f;

  for (int kt = 0; kt < 8; kt++) {
    const int jg = chunk*512 + kt*64;
    const size_t rb = ((size_t)b*SEQ + jg + i) * 2048;
#pragma unroll
    for (int jj = 0; jj < 4; jj++) {
      *(float4*)&Ks[i][db + jj*4] = *(const float4*)&KV[rb + h*64 + db + jj*4];
      *(float4*)&Vs[i][db + jj*4] = *(const float4*)&KV[rb + 1024 + h*64 + db + jj*4];
    }
    __syncthreads();

    float s[16];
#pragma unroll
    for (int jj = 0; jj < 16; jj++) {
      const int j = db + jj;
      float4 a4 = make_float4(0.f, 0.f, 0.f, 0.f);
#pragma unroll
      for (int dd = 0; dd < 16; dd++) {
        const int c = (4*dd + rot) & 63;
        const float4 kv = *(const float4*)&Ks[j][c];
        a4.x += qreg[dd].x*kv.x; a4.y += qreg[dd].y*kv.y;
        a4.z += qreg[dd].z*kv.z; a4.w += qreg[dd].w*kv.w;
      }
      s[jj] = (a4.x + a4.y + a4.z + a4.w) * SCALE;
    }
    float mt = s[0];
#pragma unroll
    for (int jj = 1; jj < 16; jj++) mt = fmaxf(mt, s[jj]);
    mt = fmaxf(mt, __shfl_xor(mt, 1));
    mt = fmaxf(mt, __shfl_xor(mt, 2));
    const float m_new = fmaxf(m_i, mt);
    const float fac = __expf(m_i - m_new);
    l_i *= fac;
#pragma unroll
    for (int dd = 0; dd < 16; dd++) o[dd] *= fac;
    float ps = 0.f;
#pragma unroll
    for (int jj = 0; jj < 16; jj++) {
      const float p = __expf(s[jj] - m_new);
      Ps[i][db + jj] = p;
      ps += p;
    }
    ps += __shfl_xor(ps, 1);
    ps += __shfl_xor(ps, 2);
    l_i += ps;
    m_i = m_new;
    __syncthreads();              // Ps visible to sibling lanes
    for (int j = 0; j < 64; j++) {
      const float w = Ps[i][j];
#pragma unroll
      for (int dd = 0; dd < 16; dd += 4) {
        const float4 vv = *(const float4*)&Vs[j][db + dd];
        o[dd+0] += w*vv.x; o[dd+1] += w*vv.y; o[dd+2] += w*vv.z; o[dd+3] += w*vv.w;
      }
    }
    __syncthreads();              // done with Ks/Vs/Ps before next stage
  }
  const int bh = b*NHEADS + h;
  const size_t ob = ((size_t)(bh*8 + chunk)*64 + i)*64 + db;
#pragma unroll
  for (int dd = 0; dd < 16; dd++) oPart[ob + dd] = o[dd];
  if (q == 0) {
    mPart[(bh*8 + chunk)*64 + i] = m_i;
    lPart[(bh*8 + chunk)*64 + i] = l_i;
  }
}

// combine 8 flash partials -> z [B*64 x 1024] as bf16 hi/lo. grid (H, B).
__global__ __launch_bounds__(256) void attn1_combine_kernel(
    const float* __restrict__ mPart, const float* __restrict__ lPart,
    const float* __restrict__ oPart,
    unsigned short* __restrict__ Zh, unsigned short* __restrict__ Zl)
{
  const int h = blockIdx.x, b = blockIdx.y;
  const int tid = threadIdx.x;
  const int i = tid >> 2, q = tid & 3, db = q * 16;
  const int bh = b*NHEADS + h;
  float mv[8];
  float M = -__builtin_inff();
#pragma unroll
  for (int c = 0; c < 8; c++) { mv[c] = mPart[(bh*8 + c)*64 + i]; M = fmaxf(M, mv[c]); }
  float Lt = 0.f, w[8];
#pragma unroll
  for (int c = 0; c < 8; c++) { w[c] = __expf(mv[c] - M); Lt += lPart[(bh*8 + c)*64 + i] * w[c]; }
  float o[16];
#pragma unroll
  for (int dd = 0; dd < 16; dd++) o[dd] = 0.f;
#pragma unroll
  for (int c = 0; c < 8; c++) {
    const float* ob = oPart + ((size_t)(bh*8 + c)*64 + i)*64 + db;
#pragma unroll
    for (int dd = 0; dd < 16; dd += 4) {
      const float4 v = *(const float4*)(ob + dd);
      o[dd+0] += w[c]*v.x; o[dd+1] += w[c]*v.y; o[dd+2] += w[c]*v.z; o[dd+3] += w[c]*v.w;
    }
  }
  const float inv = 1.f / Lt;
  const size_t ob2 = ((size_t)b*64 + i)*1024 + h*64 + db;
  write_split16(Zh + ob2, Zl + ob2, o, inv);
}

// ---------------------------------------------------------------------------
// Small attention (64 keys), stages 2 & 3. Q in registers (rotated),
// split bf16 hi/lo output. grid: (q_tiles, H, B), block 256.
// ---------------------------------------------------------------------------
__global__ __launch_bounds__(256) void attn_small_kernel(
    const float* __restrict__ Qp, int ldq, int qrows_per_b,
    const float* __restrict__ Kp, int ldk,
    const float* __restrict__ Vp, int ldv,
    unsigned short* __restrict__ Oh, unsigned short* __restrict__ Ol, int ldo)
{
  __shared__ float Ks[64][68], Vs[64][68], Ps[64][68];
  const int tid = threadIdx.x;
  const int tt = blockIdx.x, h = blockIdx.y, b = blockIdx.z;
  const int i = tid >> 2, q = tid & 3, db = q * 16, rot = q * 20;
  const size_t qrow = (size_t)b*qrows_per_b + (size_t)tt*64 + i;
  const size_t krow = (size_t)b*64 + i;

  float4 qreg[16];
#pragma unroll
  for (int dd = 0; dd < 16; dd++) {
    const int c = (4*dd + rot) & 63;
    qreg[dd] = *(const float4*)&Qp[qrow*ldq + h*64 + c];
  }
#pragma unroll
  for (int jj = 0; jj < 4; jj++) {
    *(float4*)&Ks[i][db + jj*4] = *(const float4*)&Kp[krow*ldk + h*64 + db + jj*4];
    *(float4*)&Vs[i][db + jj*4] = *(const float4*)&Vp[krow*ldv + h*64 + db + jj*4];
  }
  __syncthreads();

  float s[16];
#pragma unroll
  for (int jj = 0; jj < 16; jj++) {
    const int j = db + jj;
    float4 a4 = make_float4(0.f, 0.f, 0.f, 0.f);
#pragma unroll
    for (int dd = 0; dd < 16; dd++) {
      const int c = (4*dd + rot) & 63;
      const float4 kv = *(const float4*)&Ks[j][c];
      a4.x += qreg[dd].x*kv.x; a4.y += qreg[dd].y*kv.y;
      a4.z += qreg[dd].z*kv.z; a4.w += qreg[dd].w*kv.w;
    }
    s[jj] = (a4.x + a4.y + a4.z + a4.w) * SCALE;
  }
  float m = s[0];
#pragma unroll
  for (int jj = 1; jj < 16; jj++) m = fmaxf(m, s[jj]);
  m = fmaxf(m, __shfl_xor(m, 1));
  m = fmaxf(m, __shfl_xor(m, 2));
  float l = 0.f;
#pragma unroll
  for (int jj = 0; jj < 16; jj++) {
    const float p = __expf(s[jj] - m);
    Ps[i][db + jj] = p;
    l += p;
  }
  l += __shfl_xor(l, 1);
  l += __shfl_xor(l, 2);
  __syncthreads();
  float o[16];
#pragma unroll
  for (int dd = 0; dd < 16; dd++) o[dd] = 0.f;
  for (int j = 0; j < 64; j++) {
    const float w = Ps[i][j];
#pragma unroll
    for (int dd = 0; dd < 16; dd += 4) {
      const float4 vv = *(const float4*)&Vs[j][db + dd];
      o[dd+0] += w*vv.x; o[dd+1] += w*vv.y; o[dd+2] += w*vv.z; o[dd+3] += w*vv.w;
    }
  }
  const float inv = 1.f / l;
  const size_t ob = qrow*ldo + h*64 + db;
  write_split16(Oh + ob, Ol + ob, o, inv);
}

// ---------------------------------------------------------------------------
extern "C" void kernel_launch(void* const* d_in, const int* in_sizes, int n_in,
                              void* d_out, int out_size, void* d_ws, size_t ws_size,
                              hipStream_t stream)
{
  const float* x      = (const float*)d_in[0];
  const float* L      = (const float*)d_in[1];
  const float* Wq_lat = (const float*)d_in[2];
  const float* Wk_in  = (const float*)d_in[3];
  const float* Wv_in  = (const float*)d_in[4];
  const float* Wq_in  = (const float*)d_in[5];
  const float* Wk_lat = (const float*)d_in[6];
  const float* Wv_lat = (const float*)d_in[7];
  const float* Wout   = (const float*)d_in[8];
  float* out = (float*)d_out;
  (void)in_sizes; (void)n_in; (void)out_size; (void)ws_size;

  char* ws = (char*)d_ws;
  size_t off = 0;
  auto alloc = [&](size_t bytes) -> char* {
    char* p = ws + off; off += (bytes + 255) & ~(size_t)255; return p;
  };
  // pre-split weights [N x K] bf16 hi/lo
  unsigned short* wtKV_h  = (unsigned short*)alloc(2048ull*2048*2);
  unsigned short* wtKV_l  = (unsigned short*)alloc(2048ull*2048*2);
  unsigned short* wtQin_h = (unsigned short*)alloc(1024ull*2048*2);
  unsigned short* wtQin_l = (unsigned short*)alloc(1024ull*2048*2);
  unsigned short* wtLat_h = (unsigned short*)alloc(3072ull*1024*2);
  unsigned short* wtLat_l = (unsigned short*)alloc(3072ull*1024*2);
  unsigned short* wtOut_h = (unsigned short*)alloc(2048ull*1024*2);
  unsigned short* wtOut_l = (unsigned short*)alloc(2048ull*1024*2);
  // pre-split activations
  unsigned short* xh    = (unsigned short*)alloc(16384ull*2048*2);
  unsigned short* xl    = (unsigned short*)alloc(16384ull*2048*2);
  unsigned short* Lh    = (unsigned short*)alloc(64ull*1024*2);
  unsigned short* Ll    = (unsigned short*)alloc(64ull*1024*2);
  unsigned short* zh    = (unsigned short*)alloc(256ull*1024*2);
  unsigned short* zl    = (unsigned short*)alloc(256ull*1024*2);
  unsigned short* z2h   = (unsigned short*)alloc(256ull*1024*2);
  unsigned short* z2l   = (unsigned short*)alloc(256ull*1024*2);
  // fp32 intermediates
  float* qlat  = (float*)alloc(64ull*1024*4);
  float* zqkv  = (float*)alloc(256ull*3072*4);
  float* z2kv  = (float*)alloc(256ull*2048*4);
  float* mPart = (float*)alloc(4ull*16*8*64*4);
  float* lPart = (float*)alloc(4ull*16*8*64*4);
  float* oPart = (float*)alloc(4ull*16*8*64*64*4);
  float* big   = (float*)alloc(16384ull*2048*4);   // phase 1: [K|V]
  float* qx    = big;                               // phase 2: Qx (K region)
  unsigned short* xlat_h = (unsigned short*)(big + 16384ull*1024);          // V region
  unsigned short* xlat_l = xlat_h + 16384ull*1024;

  dim3 blk(256);

  // 1) weight prep (transpose + split)
  prep_weight_kernel<<<dim3(32, 16), blk, 0, stream>>>(Wk_in, 2048, 1024, wtKV_h, wtKV_l);
  prep_weight_kernel<<<dim3(32, 16), blk, 0, stream>>>(Wv_in, 2048, 1024, wtKV_h + 1024ull*2048, wtKV_l + 1024ull*2048);
  prep_weight_kernel<<<dim3(32, 16), blk, 0, stream>>>(Wq_in, 2048, 1024, wtQin_h, wtQin_l);
  prep_weight_kernel<<<dim3(16, 16), blk, 0, stream>>>(Wq_lat, 1024, 1024, wtLat_h, wtLat_l);
  prep_weight_kernel<<<dim3(16, 16), blk, 0, stream>>>(Wk_lat, 1024, 1024, wtLat_h + 1024ull*1024, wtLat_l + 1024ull*1024);
  prep_weight_kernel<<<dim3(16, 16), blk, 0, stream>>>(Wv_lat, 1024, 1024, wtLat_h + 2048ull*1024, wtLat_l + 2048ull*1024);
  prep_weight_kernel<<<dim3(16, 32), blk, 0, stream>>>(Wout, 1024, 2048, wtOut_h, wtOut_l);
  // activation splits: x (33.5M) and L (64K)
  split_f32_kernel<<<dim3(16384), blk, 0, stream>>>(x, xh, xl, 16384*2048/8);
  split_f32_kernel<<<dim3(32), blk, 0, stream>>>(L, Lh, Ll, 64*1024/8);

  // 2) Q_lat = L @ W_q_lat  [64 x 1024]
  gemm_dma_kernel<<<dim3(1, 8), blk, 0, stream>>>(Lh, Ll, wtLat_h, wtLat_l, qlat, 64, 1024, 1024);
  // 3) [K|V] = x @ [Wk_in|Wv_in]  [16384 x 2048]
  gemm_dma_kernel<<<dim3(64, 16), blk, 0, stream>>>(xh, xl, wtKV_h, wtKV_l, big, 16384, 2048, 2048);
  // 4) stage-1 flash attention -> z (split)
  attn1_kernel<<<dim3(8, 16, 4), blk, 0, stream>>>(qlat, big, mPart, lPart, oPart);
  attn1_combine_kernel<<<dim3(16, 4), blk, 0, stream>>>(mPart, lPart, oPart, zh, zl);
  // 5) [Ql|Kl|Vl] = z @ [Wq_lat|Wk_lat|Wv_lat]  [256 x 3072]
  gemm_dma_kernel<<<dim3(1, 24), blk, 0, stream>>>(zh, zl, wtLat_h, wtLat_l, zqkv, 256, 3072, 1024);
  // 6) stage-2 latent self-attention -> z2 (split)
  attn_small_kernel<<<dim3(1, 16, 4), blk, 0, stream>>>(zqkv, 3072, 64, zqkv + 1024, 3072, zqkv + 2048, 3072, z2h, z2l, 1024);
  // 7) [Kz|Vz] = z2 @ [Wk_lat|Wv_lat]  [256 x 2048]
  gemm_dma_kernel<<<dim3(1, 16), blk, 0, stream>>>(z2h, z2l, wtLat_h + 1024ull*1024, wtLat_l + 1024ull*1024, z2kv, 256, 2048, 1024);
  // 8) Qx = x @ Wq_in  [16384 x 1024]  (reuses K region of `big`)
  gemm_dma_kernel<<<dim3(64, 8), blk, 0, stream>>>(xh, xl, wtQin_h, wtQin_l, qx, 16384, 1024, 2048);
  // 9) stage-3 attention (tokens attend to latents) -> x_latent (split, V region)
  attn_small_kernel<<<dim3(64, 16, 4), blk, 0, stream>>>(qx, 1024, 4096, z2kv, 2048, z2kv + 1024, 2048, xlat_h, xlat_l, 1024);
  // 10) out = x_latent @ W_out  [16384 x 2048]
  gemm_dma_kernel<<<dim3(64, 16), blk, 0, stream>>>(xlat_h, xlat_l, wtOut_h, wtOut_l, out, 16384, 2048, 1024);
}

// Round 3
// 1281.960 us; speedup vs baseline: 1.3749x; 1.0518x over previous
//
#include <hip/hip_runtime.h>

// MultiLatentHeadAttention on gfx950 — round 3.
// - Heavy GEMMs: split-bf16 (hi/lo) 3-term MFMA emulation of fp32 matmul,
//   pure global_load_lds staging, LDS chunk swizzle (c -> slot (c+(R>>1))&3)
//   to kill ds_read_b128 bank conflicts.
// - Qx fused into the KV GEMM: x @ [Wk|Wv|Wq_in] -> [16384 x 3072].
// - Stage-3 attention MFMA-ized (split-S, bf16 P, split-V).

#define SEQ      4096
#define NHEADS   16
#define SCALE    0.125f   // 1/sqrt(64)

typedef short bfrag __attribute__((ext_vector_type(8)));  // 8 x bf16
typedef float facc  __attribute__((ext_vector_type(4)));  // 4 x f32 accumulator

__device__ __forceinline__ unsigned short f2bf(float f) {
  unsigned u = __float_as_uint(f);
  u += 0x7FFFu + ((u >> 16) & 1u);           // round-to-nearest-even
  return (unsigned short)(u >> 16);
}
__device__ __forceinline__ float bf2f(unsigned short h) {
  return __uint_as_float(((unsigned)h) << 16);
}
__device__ __forceinline__ unsigned pack_hl(float a, float b, unsigned &lo) {
  unsigned short ha = f2bf(a), hb = f2bf(b);
  unsigned short la = f2bf(a - bf2f(ha)), lb = f2bf(b - bf2f(hb));
  lo = (unsigned)la | ((unsigned)lb << 16);
  return (unsigned)ha | ((unsigned)hb << 16);
}
// split 8 fp32 -> hi/lo bfrag
__device__ __forceinline__ void split8(const float* f, bfrag &h, bfrag &l) {
#pragma unroll
  for (int j = 0; j < 8; j++) {
    unsigned short hi = f2bf(f[j]);
    h[j] = (short)hi;
    l[j] = (short)f2bf(f[j] - bf2f(hi));
  }
}

__device__ __forceinline__ void gl_lds16(const void* g, void* l) {
  __builtin_amdgcn_global_load_lds(
      (const __attribute__((address_space(1))) void*)g,
      (__attribute__((address_space(3))) void*)l, 16, 0, 0);
}

// write 16 fp32 (scaled by inv) as bf16 hi/lo, 2x uint4 each
__device__ __forceinline__ void write_split16(unsigned short* Hp, unsigned short* Lp,
                                              const float* o, float inv) {
  uint4 H0, H1, L0, L1;
#pragma unroll
  for (int k = 0; k < 8; k++) {
    unsigned lo;
    unsigned hi = pack_hl(o[2*k] * inv, o[2*k+1] * inv, lo);
    if (k < 4) { (&H0.x)[k] = hi; (&L0.x)[k] = lo; }
    else       { (&H1.x)[k-4] = hi; (&L1.x)[k-4] = lo; }
  }
  *(uint4*)Hp       = H0;
  *(uint4*)(Hp + 8) = H1;
  *(uint4*)Lp       = L0;
  *(uint4*)(Lp + 8) = L1;
}

// ---------------------------------------------------------------------------
// Weight prep: W [K x N] fp32 -> Th/Tl [N x K] bf16 hi/lo (transpose+split)
// grid: (K/64, N/64), block 256
// ---------------------------------------------------------------------------
__global__ __launch_bounds__(256) void prep_weight_kernel(
    const float* __restrict__ W, int K, int N,
    unsigned short* __restrict__ Th, unsigned short* __restrict__ Tl)
{
  __shared__ float tile[64][68];
  const int k0 = blockIdx.x * 64, n0 = blockIdx.y * 64;
  const int tid = threadIdx.x;
  const int r = tid >> 2, q = tid & 3;
#pragma unroll
  for (int j = 0; j < 4; j++)
    *(float4*)&tile[r][q*16 + j*4] =
        *(const float4*)&W[(size_t)(k0 + r) * N + n0 + q*16 + j*4];
  __syncthreads();
  const size_t obase = (size_t)(n0 + r) * K + k0 + q*16;
#pragma unroll
  for (int g = 0; g < 2; g++) {
    float f[8];
#pragma unroll
    for (int e = 0; e < 8; e++) f[e] = tile[q*16 + g*8 + e][r];
    uint4 H, Lo;
    H.x = pack_hl(f[0], f[1], Lo.x);
    H.y = pack_hl(f[2], f[3], Lo.y);
    H.z = pack_hl(f[4], f[5], Lo.z);
    H.w = pack_hl(f[6], f[7], Lo.w);
    *(uint4*)&Th[obase + g*8] = H;
    *(uint4*)&Tl[obase + g*8] = Lo;
  }
}

// ---------------------------------------------------------------------------
// Split fp32 array -> bf16 hi/lo (same layout). One thread per 8 elements.
// ---------------------------------------------------------------------------
__global__ __launch_bounds__(256) void split_f32_kernel(
    const float* __restrict__ X, unsigned short* __restrict__ H,
    unsigned short* __restrict__ Lo, int n8)
{
  int idx = blockIdx.x * 256 + threadIdx.x;
  if (idx >= n8) return;
  const float4 a = *(const float4*)&X[(size_t)idx*8];
  const float4 b = *(const float4*)&X[(size_t)idx*8 + 4];
  uint4 Hh, Ll;
  Hh.x = pack_hl(a.x, a.y, Ll.x);
  Hh.y = pack_hl(a.z, a.w, Ll.y);
  Hh.z = pack_hl(b.x, b.y, Ll.z);
  Hh.w = pack_hl(b.z, b.w, Ll.w);
  *(uint4*)&H[(size_t)idx*8]  = Hh;
  *(uint4*)&Lo[(size_t)idx*8] = Ll;
}

// ---------------------------------------------------------------------------
// Split-bf16 GEMM, pure-DMA staging + LDS chunk swizzle.
// C[MxN] fp32 = A (hi/lo bf16 [MxK]) @ B^T (hi/lo bf16 [NxK]).
// Block 256 thr / 4 waves; block tile 256x128; wave tile 128x64 (2m x 2n);
// BK=32. grid: (ceil(M/256), N/128). Content chunk c of row R lives at slot
// (c + (R>>1)) & 3 -> consecutive-8-lane groups of ds_read_b128 are
// conflict-free.
// ---------------------------------------------------------------------------
__global__ __launch_bounds__(256, 2) void gemm_dma_kernel(
    const unsigned short* __restrict__ Ah, const unsigned short* __restrict__ Al,
    const unsigned short* __restrict__ Bh, const unsigned short* __restrict__ Bl,
    float* __restrict__ C, int M, int N, int K)
{
  __shared__ unsigned short sAh[256*32], sAl[256*32], sBh[128*32], sBl[128*32];
  const int tid = threadIdx.x;
  const int m0 = blockIdx.x * 256, n0 = blockIdx.y * 128;
  const int wave = tid >> 6, lane = tid & 63;
  const int lrow = lane & 15, lq = lane >> 4;
  const int wm = (wave & 1) * 128, wn = (wave >> 1) * 64;

  // staging geometry: each wave-instr moves 16 rows x 64B (lane -> row lane>>2,
  // slot chunk lane&3; content chunk = (slot - (R>>1)) & 3).
  const int srow = lane >> 2, schunk = lane & 3;
  size_t aoff[4], boff[2];
#pragma unroll
  for (int j = 0; j < 4; j++) {
    const int R = 64*wave + 16*j + srow;
    int rg = m0 + R;
    if (rg > M-1) rg = M-1;
    const int c = (schunk - (R >> 1)) & 3;
    aoff[j] = ((size_t)rg * K + c*8) * 2;
  }
#pragma unroll
  for (int j = 0; j < 2; j++) {
    const int R = 32*wave + 16*j + srow;
    const int rg = n0 + R;
    const int c = (schunk - (R >> 1)) & 3;
    boff[j] = ((size_t)rg * K + c*8) * 2;
  }
  const char* Ahc = (const char*)Ah;  const char* Alc = (const char*)Al;
  const char* Bhc = (const char*)Bh;  const char* Blc = (const char*)Bl;

  facc acc[8][4] = {};

  for (int k0 = 0; k0 < K; k0 += 32) {
    const size_t kb = (size_t)k0 * 2;
#pragma unroll
    for (int j = 0; j < 4; j++) {
      gl_lds16(Ahc + aoff[j] + kb, (char*)sAh + (64*wave + 16*j)*64);
      gl_lds16(Alc + aoff[j] + kb, (char*)sAl + (64*wave + 16*j)*64);
    }
#pragma unroll
    for (int j = 0; j < 2; j++) {
      gl_lds16(Bhc + boff[j] + kb, (char*)sBh + (32*wave + 16*j)*64);
      gl_lds16(Blc + boff[j] + kb, (char*)sBl + (32*wave + 16*j)*64);
    }
    __syncthreads();   // drains vmcnt(0): DMA complete + all waves at barrier

    bfrag bh[4], bl[4];
#pragma unroll
    for (int ni = 0; ni < 4; ni++) {
      const int R = wn + ni*16 + lrow;
      const int slot = (lq + (R >> 1)) & 3;
      const int bo = R*32 + slot*8;
      bh[ni] = *(const bfrag*)&sBh[bo];
      bl[ni] = *(const bfrag*)&sBl[bo];
    }
#pragma unroll
    for (int mi = 0; mi < 8; mi++) {
      const int R = wm + mi*16 + lrow;
      const int slot = (lq + (R >> 1)) & 3;
      const int ao = R*32 + slot*8;
      const bfrag ah = *(const bfrag*)&sAh[ao];
      const bfrag al = *(const bfrag*)&sAl[ao];
#pragma unroll
      for (int ni = 0; ni < 4; ni++) {
        acc[mi][ni] = __builtin_amdgcn_mfma_f32_16x16x32_bf16(ah, bh[ni], acc[mi][ni], 0, 0, 0);
        acc[mi][ni] = __builtin_amdgcn_mfma_f32_16x16x32_bf16(ah, bl[ni], acc[mi][ni], 0, 0, 0);
        acc[mi][ni] = __builtin_amdgcn_mfma_f32_16x16x32_bf16(al, bh[ni], acc[mi][ni], 0, 0, 0);
      }
    }
    __syncthreads();   // all waves done reading LDS before next DMA lands
  }

  // epilogue: C/D layout col=lane&15, row=(lane>>4)*4+reg
#pragma unroll
  for (int mi = 0; mi < 8; mi++) {
#pragma unroll
    for (int r = 0; r < 4; r++) {
      const int row = m0 + wm + mi*16 + lq*4 + r;
      if (row < M) {
        float* Crow = C + (size_t)row * N + n0 + wn + lrow;
#pragma unroll
        for (int ni = 0; ni < 4; ni++)
          Crow[ni*16] = acc[mi][ni][r];
      }
    }
  }
}

// ---------------------------------------------------------------------------
// Stage-1 cross attention (64 latents attend to 4096 tokens), flash partials.
// grid: (8 chunks, H, B), block 256. KV rows have stride 3072 now (fused QKV).
// ---------------------------------------------------------------------------
__global__ __launch_bounds__(256) void attn1_kernel(
    const float* __restrict__ Qlat,   // [64 x 1024]
    const float* __restrict__ KV,     // [B*T x 3072], K cols 0..1023, V 1024..2047
    float* __restrict__ mPart, float* __restrict__ lPart, float* __restrict__ oPart)
{
  __shared__ float Ks[64][68], Vs[64][68], Ps[64][68];
  const int tid = threadIdx.x;
  const int chunk = blockIdx.x, h = blockIdx.y, b = blockIdx.z;
  const int i = tid >> 2, q = tid & 3, db = q * 16, rot = q * 20;

  float4 qreg[16];
#pragma unroll
  for (int dd = 0; dd < 16; dd++) {
    const int c = (4*dd + rot) & 63;
    qreg[dd] = *(const float4*)&Qlat[(size_t)i*1024 + h*64 + c];
  }
  float m_i = -__builtin_inff(), l_i = 0.f;
  float o[16];
#pragma unroll
  for (int dd = 0; dd < 16; dd++) o[dd] = 0.f;

  for (int kt = 0; kt < 8; kt++) {
    const int jg = chunk*512 + kt*64;
    const size_t rb = ((size_t)b*SEQ + jg + i) * 3072;
#pragma unroll
    for (int jj = 0; jj < 4; jj++) {
      *(float4*)&Ks[i][db + jj*4] = *(const float4*)&KV[rb + h*64 + db + jj*4];
      *(float4*)&Vs[i][db + jj*4] = *(const float4*)&KV[rb + 1024 + h*64 + db + jj*4];
    }
    __syncthreads();

    float s[16];
#pragma unroll
    for (int jj = 0; jj < 16; jj++) {
      const int j = db + jj;
      float4 a4 = make_float4(0.f, 0.f, 0.f, 0.f);
#pragma unroll
      for (int dd = 0; dd < 16; dd++) {
        const int c = (4*dd + rot) & 63;
        const float4 kv = *(const float4*)&Ks[j][c];
        a4.x += qreg[dd].x*kv.x; a4.y += qreg[dd].y*kv.y;
        a4.z += qreg[dd].z*kv.z; a4.w += qreg[dd].w*kv.w;
      }
      s[jj] = (a4.x + a4.y + a4.z + a4.w) * SCALE;
    }
    float mt = s[0];
#pragma unroll
    for (int jj = 1; jj < 16; jj++) mt = fmaxf(mt, s[jj]);
    mt = fmaxf(mt, __shfl_xor(mt, 1));
    mt = fmaxf(mt, __shfl_xor(mt, 2));
    const float m_new = fmaxf(m_i, mt);
    const float fac = __expf(m_i - m_new);
    l_i *= fac;
#pragma unroll
    for (int dd = 0; dd < 16; dd++) o[dd] *= fac;
    float ps = 0.f;
#pragma unroll
    for (int jj = 0; jj < 16; jj++) {
      const float p = __expf(s[jj] - m_new);
      Ps[i][db + jj] = p;
      ps += p;
    }
    ps += __shfl_xor(ps, 1);
    ps += __shfl_xor(ps, 2);
    l_i += ps;
    m_i = m_new;
    __syncthreads();              // Ps visible to sibling lanes
    for (int j = 0; j < 64; j++) {
      const float w = Ps[i][j];
#pragma unroll
      for (int dd = 0; dd < 16; dd += 4) {
        const float4 vv = *(const float4*)&Vs[j][db + dd];
        o[dd+0] += w*vv.x; o[dd+1] += w*vv.y; o[dd+2] += w*vv.z; o[dd+3] += w*vv.w;
      }
    }
    __syncthreads();              // done with Ks/Vs/Ps before next stage
  }
  const int bh = b*NHEADS + h;
  const size_t ob = ((size_t)(bh*8 + chunk)*64 + i)*64 + db;
#pragma unroll
  for (int dd = 0; dd < 16; dd++) oPart[ob + dd] = o[dd];
  if (q == 0) {
    mPart[(bh*8 + chunk)*64 + i] = m_i;
    lPart[(bh*8 + chunk)*64 + i] = l_i;
  }
}

// combine 8 flash partials -> z [B*64 x 1024] as bf16 hi/lo. grid (H, B).
__global__ __launch_bounds__(256) void attn1_combine_kernel(
    const float* __restrict__ mPart, const float* __restrict__ lPart,
    const float* __restrict__ oPart,
    unsigned short* __restrict__ Zh, unsigned short* __restrict__ Zl)
{
  const int h = blockIdx.x, b = blockIdx.y;
  const int tid = threadIdx.x;
  const int i = tid >> 2, q = tid & 3, db = q * 16;
  const int bh = b*NHEADS + h;
  float mv[8];
  float M = -__builtin_inff();
#pragma unroll
  for (int c = 0; c < 8; c++) { mv[c] = mPart[(bh*8 + c)*64 + i]; M = fmaxf(M, mv[c]); }
  float Lt = 0.f, w[8];
#pragma unroll
  for (int c = 0; c < 8; c++) { w[c] = __expf(mv[c] - M); Lt += lPart[(bh*8 + c)*64 + i] * w[c]; }
  float o[16];
#pragma unroll
  for (int dd = 0; dd < 16; dd++) o[dd] = 0.f;
#pragma unroll
  for (int c = 0; c < 8; c++) {
    const float* ob = oPart + ((size_t)(bh*8 + c)*64 + i)*64 + db;
#pragma unroll
    for (int dd = 0; dd < 16; dd += 4) {
      const float4 v = *(const float4*)(ob + dd);
      o[dd+0] += w[c]*v.x; o[dd+1] += w[c]*v.y; o[dd+2] += w[c]*v.z; o[dd+3] += w[c]*v.w;
    }
  }
  const float inv = 1.f / Lt;
  const size_t ob2 = ((size_t)b*64 + i)*1024 + h*64 + db;
  write_split16(Zh + ob2, Zl + ob2, o, inv);
}

// ---------------------------------------------------------------------------
// Small attention (64 keys), stage 2. Q in registers (rotated),
// split bf16 hi/lo output. grid: (1, H, B), block 256.
// ---------------------------------------------------------------------------
__global__ __launch_bounds__(256) void attn_small_kernel(
    const float* __restrict__ Qp, int ldq, int qrows_per_b,
    const float* __restrict__ Kp, int ldk,
    const float* __restrict__ Vp, int ldv,
    unsigned short* __restrict__ Oh, unsigned short* __restrict__ Ol, int ldo)
{
  __shared__ float Ks[64][68], Vs[64][68], Ps[64][68];
  const int tid = threadIdx.x;
  const int tt = blockIdx.x, h = blockIdx.y, b = blockIdx.z;
  const int i = tid >> 2, q = tid & 3, db = q * 16, rot = q * 20;
  const size_t qrow = (size_t)b*qrows_per_b + (size_t)tt*64 + i;
  const size_t krow = (size_t)b*64 + i;

  float4 qreg[16];
#pragma unroll
  for (int dd = 0; dd < 16; dd++) {
    const int c = (4*dd + rot) & 63;
    qreg[dd] = *(const float4*)&Qp[qrow*ldq + h*64 + c];
  }
#pragma unroll
  for (int jj = 0; jj < 4; jj++) {
    *(float4*)&Ks[i][db + jj*4] = *(const float4*)&Kp[krow*ldk + h*64 + db + jj*4];
    *(float4*)&Vs[i][db + jj*4] = *(const float4*)&Vp[krow*ldv + h*64 + db + jj*4];
  }
  __syncthreads();

  float s[16];
#pragma unroll
  for (int jj = 0; jj < 16; jj++) {
    const int j = db + jj;
    float4 a4 = make_float4(0.f, 0.f, 0.f, 0.f);
#pragma unroll
    for (int dd = 0; dd < 16; dd++) {
      const int c = (4*dd + rot) & 63;
      const float4 kv = *(const float4*)&Ks[j][c];
      a4.x += qreg[dd].x*kv.x; a4.y += qreg[dd].y*kv.y;
      a4.z += qreg[dd].z*kv.z; a4.w += qreg[dd].w*kv.w;
    }
    s[jj] = (a4.x + a4.y + a4.z + a4.w) * SCALE;
  }
  float m = s[0];
#pragma unroll
  for (int jj = 1; jj < 16; jj++) m = fmaxf(m, s[jj]);
  m = fmaxf(m, __shfl_xor(m, 1));
  m = fmaxf(m, __shfl_xor(m, 2));
  float l = 0.f;
#pragma unroll
  for (int jj = 0; jj < 16; jj++) {
    const float p = __expf(s[jj] - m);
    Ps[i][db + jj] = p;
    l += p;
  }
  l += __shfl_xor(l, 1);
  l += __shfl_xor(l, 2);
  __syncthreads();
  float o[16];
#pragma unroll
  for (int dd = 0; dd < 16; dd++) o[dd] = 0.f;
  for (int j = 0; j < 64; j++) {
    const float w = Ps[i][j];
#pragma unroll
    for (int dd = 0; dd < 16; dd += 4) {
      const float4 vv = *(const float4*)&Vs[j][db + dd];
      o[dd+0] += w*vv.x; o[dd+1] += w*vv.y; o[dd+2] += w*vv.z; o[dd+3] += w*vv.w;
    }
  }
  const float inv = 1.f / l;
  const size_t ob = qrow*ldo + h*64 + db;
  write_split16(Oh + ob, Ol + ob, o, inv);
}

// ---------------------------------------------------------------------------
// Stage-3 attention, MFMA version. 16384 tokens attend to 64 latents.
// grid: (64 qtiles, H, B), block 256 = 4 waves; each wave: 16 q-rows.
// S = Qx @ Kz^T via 3-term split MFMA; softmax in C-layout; P -> bf16 via
// per-wave LDS tile; O = P @ V with V split (2 terms). Output split bf16.
// ---------------------------------------------------------------------------
__global__ __launch_bounds__(256) void attn3_mfma_kernel(
    const float* __restrict__ QKV,    // [16384 x 3072], Qx at cols 2048..3071
    const float* __restrict__ z2kv,   // [256 x 2048], Kz cols 0..1023, Vz 1024..2047
    unsigned short* __restrict__ Oh, unsigned short* __restrict__ Ol)  // [16384 x 1024]
{
  __shared__ unsigned short Pb[4][16][72];   // per-wave P tile, pad 72 (2-way free)
  const int tid = threadIdx.x;
  const int wave = tid >> 6, lane = tid & 63;
  const int lrow = lane & 15, lq = lane >> 4;
  const int qt = blockIdx.x, h = blockIdx.y, b = blockIdx.z;
  const size_t tok0 = (size_t)b*SEQ + qt*64 + wave*16;   // first token of this wave

  // ---- Q A-frags (fp32 -> hi/lo), k = ks*32 + lq*8 + j
  bfrag qh[2], ql[2];
  {
    const float* qp = QKV + (tok0 + lrow)*3072 + 2048 + h*64 + lq*8;
#pragma unroll
    for (int ks = 0; ks < 2; ks++) {
      float f[8];
      *(float4*)&f[0] = *(const float4*)(qp + ks*32);
      *(float4*)&f[4] = *(const float4*)(qp + ks*32 + 4);
      split8(f, qh[ks], ql[ks]);
    }
  }
  // ---- Kz B-frags: element (k = ks*32+lq*8+j, n = ni*16+lrow) = Kz[n][k]
  bfrag kh[4][2], kl[4][2];
#pragma unroll
  for (int ni = 0; ni < 4; ni++) {
    const float* kp = z2kv + (size_t)(b*64 + ni*16 + lrow)*2048 + h*64 + lq*8;
#pragma unroll
    for (int ks = 0; ks < 2; ks++) {
      float f[8];
      *(float4*)&f[0] = *(const float4*)(kp + ks*32);
      *(float4*)&f[4] = *(const float4*)(kp + ks*32 + 4);
      split8(f, kh[ni][ks], kl[ni][ks]);
    }
  }
  // ---- S = Q @ Kz^T (3-term split)
  facc s[4] = {};
#pragma unroll
  for (int ni = 0; ni < 4; ni++)
#pragma unroll
    for (int ks = 0; ks < 2; ks++) {
      s[ni] = __builtin_amdgcn_mfma_f32_16x16x32_bf16(qh[ks], kh[ni][ks], s[ni], 0, 0, 0);
      s[ni] = __builtin_amdgcn_mfma_f32_16x16x32_bf16(qh[ks], kl[ni][ks], s[ni], 0, 0, 0);
      s[ni] = __builtin_amdgcn_mfma_f32_16x16x32_bf16(ql[ks], kh[ni][ks], s[ni], 0, 0, 0);
    }
  // ---- softmax per row (row = lq*4 + r; cols = ni*16 + (lane&15) across 16 lanes)
  float inv[4];
  float p[4][4];  // [ni][r]
#pragma unroll
  for (int r = 0; r < 4; r++) {
    float mx = fmaxf(fmaxf(s[0][r], s[1][r]), fmaxf(s[2][r], s[3][r])) * SCALE;
    mx = fmaxf(mx, __shfl_xor(mx, 1));
    mx = fmaxf(mx, __shfl_xor(mx, 2));
    mx = fmaxf(mx, __shfl_xor(mx, 4));
    mx = fmaxf(mx, __shfl_xor(mx, 8));
    float sum = 0.f;
#pragma unroll
    for (int ni = 0; ni < 4; ni++) {
      p[ni][r] = __expf(s[ni][r] * SCALE - mx);
      sum += p[ni][r];
    }
    sum += __shfl_xor(sum, 1);
    sum += __shfl_xor(sum, 2);
    sum += __shfl_xor(sum, 4);
    sum += __shfl_xor(sum, 8);
    inv[r] = 1.f / sum;
  }
  // ---- P -> bf16 in LDS (C-layout write, A-layout read)
#pragma unroll
  for (int ni = 0; ni < 4; ni++)
#pragma unroll
    for (int r = 0; r < 4; r++)
      Pb[wave][lq*4 + r][ni*16 + lrow] = f2bf(p[ni][r]);
  __asm__ volatile("s_waitcnt lgkmcnt(0)" ::: "memory");
  bfrag pa[2];
#pragma unroll
  for (int ks = 0; ks < 2; ks++)
    pa[ks] = *(const bfrag*)&Pb[wave][lrow][ks*32 + lq*8];
  // ---- Vz B-frags: element (k = latent j = ks*32+lq*8+jj, n = dim = ni*16+lrow)
  //      = Vz[j][n]; strided scalar loads, coalesced across lrow, L2-hot.
  facc o[4] = {};
#pragma unroll
  for (int ni = 0; ni < 4; ni++) {
#pragma unroll
    for (int ks = 0; ks < 2; ks++) {
      float f[8];
#pragma unroll
      for (int jj = 0; jj < 8; jj++)
        f[jj] = z2kv[(size_t)(b*64 + ks*32 + lq*8 + jj)*2048 + 1024 + h*64 + ni*16 + lrow];
      bfrag vh, vl;
      split8(f, vh, vl);
      o[ni] = __builtin_amdgcn_mfma_f32_16x16x32_bf16(pa[ks], vh, o[ni], 0, 0, 0);
      o[ni] = __builtin_amdgcn_mfma_f32_16x16x32_bf16(pa[ks], vl, o[ni], 0, 0, 0);
    }
  }
  // ---- epilogue: row = lq*4+r, col = h*64 + ni*16 + lrow; split bf16 out
#pragma unroll
  for (int ni = 0; ni < 4; ni++) {
#pragma unroll
    for (int r = 0; r < 4; r++) {
      const float v = o[ni][r] * inv[r];
      const unsigned short hi = f2bf(v);
      const unsigned short lo = f2bf(v - bf2f(hi));
      const size_t idx = (tok0 + lq*4 + r)*1024 + h*64 + ni*16 + lrow;
      Oh[idx] = hi;
      Ol[idx] = lo;
    }
  }
}

// ---------------------------------------------------------------------------
extern "C" void kernel_launch(void* const* d_in, const int* in_sizes, int n_in,
                              void* d_out, int out_size, void* d_ws, size_t ws_size,
                              hipStream_t stream)
{
  const float* x      = (const float*)d_in[0];
  const float* L      = (const float*)d_in[1];
  const float* Wq_lat = (const float*)d_in[2];
  const float* Wk_in  = (const float*)d_in[3];
  const float* Wv_in  = (const float*)d_in[4];
  const float* Wq_in  = (const float*)d_in[5];
  const float* Wk_lat = (const float*)d_in[6];
  const float* Wv_lat = (const float*)d_in[7];
  const float* Wout   = (const float*)d_in[8];
  float* out = (float*)d_out;
  (void)in_sizes; (void)n_in; (void)out_size; (void)ws_size;

  char* ws = (char*)d_ws;
  size_t off = 0;
  auto alloc = [&](size_t bytes) -> char* {
    char* p = ws + off; off += (bytes + 255) & ~(size_t)255; return p;
  };
  // pre-split weights [N x K] bf16 hi/lo. wtKVQ = [Wk_in|Wv_in|Wq_in]^T.
  unsigned short* wtKVQ_h = (unsigned short*)alloc(3072ull*2048*2);
  unsigned short* wtKVQ_l = (unsigned short*)alloc(3072ull*2048*2);
  unsigned short* wtLat_h = (unsigned short*)alloc(3072ull*1024*2);
  unsigned short* wtLat_l = (unsigned short*)alloc(3072ull*1024*2);
  unsigned short* wtOut_h = (unsigned short*)alloc(2048ull*1024*2);
  unsigned short* wtOut_l = (unsigned short*)alloc(2048ull*1024*2);
  // pre-split activations
  unsigned short* xh    = (unsigned short*)alloc(16384ull*2048*2);
  unsigned short* xl    = (unsigned short*)alloc(16384ull*2048*2);
  unsigned short* Lh    = (unsigned short*)alloc(64ull*1024*2);
  unsigned short* Ll    = (unsigned short*)alloc(64ull*1024*2);
  unsigned short* zh    = (unsigned short*)alloc(256ull*1024*2);
  unsigned short* zl    = (unsigned short*)alloc(256ull*1024*2);
  unsigned short* z2h   = (unsigned short*)alloc(256ull*1024*2);
  unsigned short* z2l   = (unsigned short*)alloc(256ull*1024*2);
  // fp32 intermediates
  float* qlat  = (float*)alloc(64ull*1024*4);
  float* zqkv  = (float*)alloc(256ull*3072*4);
  float* z2kv  = (float*)alloc(256ull*2048*4);
  float* mPart = (float*)alloc(4ull*16*8*64*4);
  float* lPart = (float*)alloc(4ull*16*8*64*4);
  float* oPart = (float*)alloc(4ull*16*8*64*64*4);
  float* qkv   = (float*)alloc(16384ull*3072*4);   // [K|V|Qx]
  // x_latent (split) reuses xh/xl (dead after the fused QKV GEMM)
  unsigned short* xlat_h = xh;
  unsigned short* xlat_l = xl;

  dim3 blk(256);

  // 1) weight prep (transpose + split)
  prep_weight_kernel<<<dim3(32, 16), blk, 0, stream>>>(Wk_in, 2048, 1024, wtKVQ_h, wtKVQ_l);
  prep_weight_kernel<<<dim3(32, 16), blk, 0, stream>>>(Wv_in, 2048, 1024, wtKVQ_h + 1024ull*2048, wtKVQ_l + 1024ull*2048);
  prep_weight_kernel<<<dim3(32, 16), blk, 0, stream>>>(Wq_in, 2048, 1024, wtKVQ_h + 2048ull*2048, wtKVQ_l + 2048ull*2048);
  prep_weight_kernel<<<dim3(16, 16), blk, 0, stream>>>(Wq_lat, 1024, 1024, wtLat_h, wtLat_l);
  prep_weight_kernel<<<dim3(16, 16), blk, 0, stream>>>(Wk_lat, 1024, 1024, wtLat_h + 1024ull*1024, wtLat_l + 1024ull*1024);
  prep_weight_kernel<<<dim3(16, 16), blk, 0, stream>>>(Wv_lat, 1024, 1024, wtLat_h + 2048ull*1024, wtLat_l + 2048ull*1024);
  prep_weight_kernel<<<dim3(16, 32), blk, 0, stream>>>(Wout, 1024, 2048, wtOut_h, wtOut_l);
  // activation splits: x (33.5M) and L (64K)
  split_f32_kernel<<<dim3(16384), blk, 0, stream>>>(x, xh, xl, 16384*2048/8);
  split_f32_kernel<<<dim3(32), blk, 0, stream>>>(L, Lh, Ll, 64*1024/8);

  // 2) Q_lat = L @ W_q_lat  [64 x 1024]
  gemm_dma_kernel<<<dim3(1, 8), blk, 0, stream>>>(Lh, Ll, wtLat_h, wtLat_l, qlat, 64, 1024, 1024);
  // 3) [K|V|Qx] = x @ [Wk_in|Wv_in|Wq_in]  [16384 x 3072] (fused)
  gemm_dma_kernel<<<dim3(64, 24), blk, 0, stream>>>(xh, xl, wtKVQ_h, wtKVQ_l, qkv, 16384, 3072, 2048);
  // 4) stage-1 flash attention -> z (split)
  attn1_kernel<<<dim3(8, 16, 4), blk, 0, stream>>>(qlat, qkv, mPart, lPart, oPart);
  attn1_combine_kernel<<<dim3(16, 4), blk, 0, stream>>>(mPart, lPart, oPart, zh, zl);
  // 5) [Ql|Kl|Vl] = z @ [Wq_lat|Wk_lat|Wv_lat]  [256 x 3072]
  gemm_dma_kernel<<<dim3(1, 24), blk, 0, stream>>>(zh, zl, wtLat_h, wtLat_l, zqkv, 256, 3072, 1024);
  // 6) stage-2 latent self-attention -> z2 (split)
  attn_small_kernel<<<dim3(1, 16, 4), blk, 0, stream>>>(zqkv, 3072, 64, zqkv + 1024, 3072, zqkv + 2048, 3072, z2h, z2l, 1024);
  // 7) [Kz|Vz] = z2 @ [Wk_lat|Wv_lat]  [256 x 2048]
  gemm_dma_kernel<<<dim3(1, 16), blk, 0, stream>>>(z2h, z2l, wtLat_h + 1024ull*1024, wtLat_l + 1024ull*1024, z2kv, 256, 2048, 1024);
  // 8) stage-3 attention (MFMA) -> x_latent (split, reuses xh/xl)
  attn3_mfma_kernel<<<dim3(64, 16, 4), blk, 0, stream>>>(qkv, z2kv, xlat_h, xlat_l);
  // 9) out = x_latent @ W_out  [16384 x 2048]
  gemm_dma_kernel<<<dim3(64, 16), blk, 0, stream>>>(xlat_h, xlat_l, wtOut_h, wtOut_l, out, 16384, 2048, 1024);
}